// Round 1
// baseline (142.508 us; speedup 1.0000x reference)
//
#include <hip/hip_runtime.h>
#include <math.h>

#define NEG_SLOPE 0.01f

// ---------------------------------------------------------------------------
// Stage 0: 1x1 conv (16 <- 384) + bias + leaky ReLU.
// x: (4,384,32,32), w: (16,384), b: (16), out: (4,16,32,32)
// One thread per (b, co, hw). 65536 threads total.
// ---------------------------------------------------------------------------
__global__ void linear_leaky_kernel(const float* __restrict__ x,
                                    const float* __restrict__ w,
                                    const float* __restrict__ b,
                                    float* __restrict__ out) {
    int idx = blockIdx.x * blockDim.x + threadIdx.x;   // b*16*1024 + co*1024 + hw
    int hw = idx & 1023;
    int co = (idx >> 10) & 15;
    int bb = idx >> 14;
    const float* xp = x + bb * 384 * 1024 + hw;
    const float* wp = w + co * 384;
    float acc = b[co];
#pragma unroll 8
    for (int ci = 0; ci < 384; ++ci)
        acc = fmaf(wp[ci], xp[ci * 1024], acc);
    out[idx] = acc >= 0.f ? acc : NEG_SLOPE * acc;
}

// ---------------------------------------------------------------------------
// Bilinear resize of guide (4,3,512,512) -> (4,3,R,R), align_corners=False
// style coords per the reference: c = max((o+0.5)*(512/R)-0.5, 0).
// ---------------------------------------------------------------------------
__global__ void resize_kernel(const float* __restrict__ g,
                              float* __restrict__ out, int R) {
    int idx = blockIdx.x * blockDim.x + threadIdx.x;
    int total = 4 * 3 * R * R;
    if (idx >= total) return;
    int w = idx % R;
    int h = (idx / R) % R;
    int bc = idx / (R * R);
    float scale = 512.0f / (float)R;
    float ch = fmaxf((h + 0.5f) * scale - 0.5f, 0.f);
    float cw = fmaxf((w + 0.5f) * scale - 0.5f, 0.f);
    int h0 = (int)ch;
    int w0 = (int)cw;
    int h1 = min(h0 + 1, 511);
    int w1 = min(w0 + 1, 511);
    float fh = ch - (float)h0;
    float fw = cw - (float)w0;
    const float* gp = g + (size_t)bc * 512 * 512;
    float v00 = gp[h0 * 512 + w0];
    float v01 = gp[h0 * 512 + w1];
    float v10 = gp[h1 * 512 + w0];
    float v11 = gp[h1 * 512 + w1];
    float top = v00 + (v01 - v00) * fw;
    float bot = v10 + (v11 - v10) * fw;
    out[idx] = top + (bot - top) * fh;
}

// ---------------------------------------------------------------------------
// Fused: nearest-up2 of x (implicit via h>>1 indexing) + PAC conv + activation.
// x:   (4, Ci, H/2, W/2)
// g:   (4, 3, H, W)      resized guide at output resolution
// wk:  (Co, Ci, 9)
// out: (4, Co, H, W)
// ACT: 0 = leaky ReLU, 1 = sigmoid
// OOB taps: x_unf is zero-padded at the same positions as g_unf, so the tap's
// contribution is exactly zero -> skip (kern value there is irrelevant).
// ---------------------------------------------------------------------------
template <int Ci, int Co, int ACT>
__global__ void pac_conv_kernel(const float* __restrict__ x,
                                const float* __restrict__ g,
                                const float* __restrict__ wk,
                                float* __restrict__ out,
                                int H, int W) {
    __shared__ float sw[Co * Ci * 9];
    for (int i = threadIdx.x; i < Co * Ci * 9; i += blockDim.x) sw[i] = wk[i];
    __syncthreads();

    int idx = blockIdx.x * blockDim.x + threadIdx.x;
    int total = 4 * H * W;
    if (idx >= total) return;
    int w = idx % W;
    int h = (idx / W) % H;
    int b = idx / (H * W);
    int Hh = H >> 1, Wh = W >> 1;
    int HW = H * W;

    const float* gb = g + (size_t)b * 3 * HW;
    float gc0 = gb[h * W + w];
    float gc1 = gb[HW + h * W + w];
    float gc2 = gb[2 * HW + h * W + w];

    float acc[Co];
#pragma unroll
    for (int co = 0; co < Co; ++co) acc[co] = 0.f;

    const float* xb = x + (size_t)b * Ci * Hh * Wh;

#pragma unroll
    for (int t = 0; t < 9; ++t) {
        int dh = t / 3 - 1, dw = t % 3 - 1;
        int hh = h + dh, ww = w + dw;
        if (hh < 0 || hh >= H || ww < 0 || ww >= W) continue;
        float d0 = gb[hh * W + ww] - gc0;
        float d1 = gb[HW + hh * W + ww] - gc1;
        float d2 = gb[2 * HW + hh * W + ww] - gc2;
        float k = __expf(-0.5f * (d0 * d0 + d1 * d1 + d2 * d2));
        const float* xp = xb + (hh >> 1) * Wh + (ww >> 1);
#pragma unroll
        for (int ci = 0; ci < Ci; ++ci) {
            float xv = xp[ci * Hh * Wh] * k;
#pragma unroll
            for (int co = 0; co < Co; ++co)
                acc[co] = fmaf(sw[(co * Ci + ci) * 9 + t], xv, acc[co]);
        }
    }

#pragma unroll
    for (int co = 0; co < Co; ++co) {
        float v = acc[co];
        if (ACT == 0) {
            v = v >= 0.f ? v : NEG_SLOPE * v;
        } else {
            v = 1.0f / (1.0f + __expf(-v));
        }
        out[((size_t)(b * Co + co) * HW) + h * W + w] = v;
    }
}

extern "C" void kernel_launch(void* const* d_in, const int* in_sizes, int n_in,
                              void* d_out, int out_size, void* d_ws, size_t ws_size,
                              hipStream_t stream) {
    const float* x     = (const float*)d_in[0];   // (4,384,32,32)
    const float* guide = (const float*)d_in[1];   // (4,3,512,512)
    const float* lin_w = (const float*)d_in[2];   // (16,384,1,1)
    const float* lin_b = (const float*)d_in[3];   // (16,)
    const float* w0    = (const float*)d_in[4];   // (4,16,3,3)
    const float* w1    = (const float*)d_in[5];   // (4,4,3,3)
    const float* w2    = (const float*)d_in[6];   // (4,4,3,3)
    const float* w3    = (const float*)d_in[7];   // (1,4,3,3)
    float* out = (float*)d_out;                   // (4,1,512,512)

    // Workspace layout (floats)
    float* ws = (float*)d_ws;
    float* x16  = ws;                 // 4*16*32*32   = 65536
    float* g64  = x16  + 65536;       // 4*3*64*64    = 49152
    float* x0   = g64  + 49152;       // 4*4*64*64    = 65536
    float* g128 = x0   + 65536;       // 4*3*128*128  = 196608
    float* x1   = g128 + 196608;      // 4*4*128*128  = 262144
    float* g256 = x1   + 262144;      // 4*3*256*256  = 786432
    float* x2   = g256 + 786432;      // 4*4*256*256  = 1048576

    const int B = 256;

    // Stage 0: linear + leaky
    linear_leaky_kernel<<<65536 / B, B, 0, stream>>>(x, lin_w, lin_b, x16);

    // Stage 1: guide->64, pac 16->4 @64
    resize_kernel<<<(49152 + B - 1) / B, B, 0, stream>>>(guide, g64, 64);
    pac_conv_kernel<16, 4, 0><<<(4 * 64 * 64) / B, B, 0, stream>>>(x16, g64, w0, x0, 64, 64);

    // Stage 2: guide->128, pac 4->4 @128
    resize_kernel<<<(196608 + B - 1) / B, B, 0, stream>>>(guide, g128, 128);
    pac_conv_kernel<4, 4, 0><<<(4 * 128 * 128) / B, B, 0, stream>>>(x0, g128, w1, x1, 128, 128);

    // Stage 3: guide->256, pac 4->4 @256
    resize_kernel<<<(786432 + B - 1) / B, B, 0, stream>>>(guide, g256, 256);
    pac_conv_kernel<4, 4, 0><<<(4 * 256 * 256) / B, B, 0, stream>>>(x1, g256, w2, x2, 256, 256);

    // Stage 4: pac 4->1 @512 + sigmoid, guide used at native res
    pac_conv_kernel<4, 1, 1><<<(4 * 512 * 512) / B, B, 0, stream>>>(x2, guide, w3, out, 512, 512);
}